// Round 13
// baseline (57.224 us; speedup 1.0000x reference)
//
#include <hip/hip_runtime.h>
#include <stdint.h>

#define N_DIM 256
#define C_DIM 64
#define D_DIM 4096
#define NST16 128             // K steps of 32 for the 16x16 path
#define PDEP  4               // u prefetch pipeline depth

// ws layout: uh (f16 u, 512 KB) @0; vh (f16 v, 2 MB) @1MB
#define VH_OFF   (1u << 20)

typedef __bf16    bf16x8_t __attribute__((ext_vector_type(8)));
typedef _Float16  f16x8_t  __attribute__((ext_vector_type(8)));
typedef float     f32x4_t  __attribute__((ext_vector_type(4)));
typedef float     f32x16_t __attribute__((ext_vector_type(16)));

union Frag {
  uint4     q;
  uint32_t  u[4];
  bf16x8_t  b;
};
union FragH {
  uint4     q;
  _Float16  h[8];
  f16x8_t   v;
};

__device__ __forceinline__ uint32_t pk_bf16(float lo, float hi) {
  uint32_t d;
  asm("v_cvt_pk_bf16_f32 %0, %1, %2" : "=v"(d) : "v"(lo), "v"(hi));
  return d;
}

#define MFMA16H(a, b, c) __builtin_amdgcn_mfma_f32_16x16x32_f16(a, b, c, 0, 0, 0)
#define MFMA32B(a, b, c) __builtin_amdgcn_mfma_f32_32x32x16_bf16(a, b, c, 0, 0, 0)

// ---- prep helpers (R6/R8-validated) ---------------------------------------
__device__ __forceinline__ void prep_u_unit(const float* __restrict__ u,
                                            _Float16* __restrict__ uh, int t) {
  const int row = t >> 9;
  const int k8  = t & 511;
  const float4* p = (const float4*)(u + (size_t)row * D_DIM + (size_t)k8 * 8);
  const float4 a = p[0], b = p[1];
  FragH o;
  o.h[0] = (_Float16)a.x; o.h[1] = (_Float16)a.y;
  o.h[2] = (_Float16)a.z; o.h[3] = (_Float16)a.w;
  o.h[4] = (_Float16)b.x; o.h[5] = (_Float16)b.y;
  o.h[6] = (_Float16)b.z; o.h[7] = (_Float16)b.w;
  *(uint4*)(uh + (size_t)(k8 * C_DIM + row) * 8) = o.q;
}

__device__ __forceinline__ void prep_v_unit(const float* __restrict__ v,
                                            _Float16* __restrict__ vh, int t) {
  const float4* p = (const float4*)(v + (size_t)t * 8);
  const float4 a = p[0], b = p[1];
  FragH o;
  o.h[0] = (_Float16)a.x; o.h[1] = (_Float16)a.y;
  o.h[2] = (_Float16)a.z; o.h[3] = (_Float16)a.w;
  o.h[4] = (_Float16)b.x; o.h[5] = (_Float16)b.y;
  o.h[6] = (_Float16)b.z; o.h[7] = (_Float16)b.w;
  *(uint4*)(vh + (size_t)t * 8) = o.q;
}

__global__ __launch_bounds__(256) void prep_kernel(const float* __restrict__ u,
                                                   const float* __restrict__ v,
                                                   _Float16* __restrict__ uh,
                                                   _Float16* __restrict__ vh) {
  const int gid = blockIdx.x * 256 + threadIdx.x;
  if (blockIdx.x < 128) prep_u_unit(u, uh, gid);
  else                  prep_v_unit(v, vh, gid - 32768);
}

// ---- gram: 16x16 tiles, full-K per wave, NO cross-wave reduction ----------
// grid 1024: block (n = bid>>2, i = bid&3); wave w computes tile (i, w).
// Every wave on a CU reads the same 4KB uh window per step -> L1 dedup.
__global__ __launch_bounds__(256, 4)
void gram_kernel(const _Float16* __restrict__ vh,
                 const _Float16* __restrict__ uh,
                 float* __restrict__ out)
{
  const int tid = threadIdx.x;
  const int w   = tid >> 6;      // tile col j = w
  const int l   = tid & 63;
  const int bid = blockIdx.x;
  const int n   = bid >> 2;
  const int ti  = bid & 3;       // tile row i
  const int g   = l >> 4;        // k-group (0..3)
  const int r   = l & 15;        // row/col within 16-tile

  f32x4_t acc;
#pragma unroll
  for (int q = 0; q < 4; ++q) acc[q] = 0.0f;

  // fragment streams: unit k8 = s*4 + g, A-row 16*ti + r, B-row 16*w + r
  const char* ua = (const char*)uh + (size_t)g * 1024 + (size_t)(16 * ti + r) * 16;
  const char* ub = (const char*)uh + (size_t)g * 1024 + (size_t)(16 * w + r) * 16;
  const char* vg = (const char*)vh + ((size_t)n * D_DIM + g * 8) * 2;

  // PDEP-deep pipeline (A,B), depth-2 v
  FragH pa[PDEP], pb[PDEP];
#pragma unroll
  for (int p = 0; p < PDEP; ++p) {
    pa[p].q = *(const uint4*)(ua + (size_t)p * 4096);
    pb[p].q = *(const uint4*)(ub + (size_t)p * 4096);
  }
  uint4 vcur = *(const uint4*)(vg);
  uint4 vnxt = *(const uint4*)(vg + 64);

#pragma unroll 4
  for (int s = 0; s < NST16 - PDEP; ++s) {
    const int cur = s % PDEP;
    FragH vv; vv.q = vcur;
    FragH sa;
    sa.v = pa[cur].v * vv.v;             // v_pk_mul_f16: scale A rows by v[k]
    acc = MFMA16H(sa.v, pb[cur].v, acc);
    pa[cur].q = *(const uint4*)(ua + (size_t)(s + PDEP) * 4096);  // refill
    pb[cur].q = *(const uint4*)(ub + (size_t)(s + PDEP) * 4096);
    vcur = vnxt;
    vnxt = *(const uint4*)(vg + (size_t)(s + 2) * 64);
    if ((s & 31) == 31) __syncthreads();  // bound intra-block k-drift (L1 reuse)
  }
#pragma unroll
  for (int s = NST16 - PDEP; s < NST16; ++s) {   // tail: no refill
    const int cur = s % PDEP;
    FragH vv; vv.q = *(const uint4*)(vg + (size_t)s * 64);
    FragH sa;
    sa.v = pa[cur].v * vv.v;
    acc = MFMA16H(sa.v, pb[cur].v, acc);
  }

  // C/D (16x16): col = l&15, row = (l>>4)*4 + q  [m89, dtype-independent]
  float* onb = out + (size_t)n * 4096 + (size_t)(16 * ti + 4 * g) * 64 + 16 * w + r;
#pragma unroll
  for (int q = 0; q < 4; ++q)
    onb[(size_t)q * 64] = acc[q];
}

// ---- fallback (tiny ws): R5/R6-validated single-kernel bf16 path ----------
__global__ __launch_bounds__(256)
void gram_fallback_kernel(const float* __restrict__ vin,
                          const float* __restrict__ uf32,
                          float* __restrict__ out)
{
  __shared__ float Red[4][C_DIM][20];

  const int tid = threadIdx.x;
  const int w   = tid >> 6;
  const int l   = tid & 63;
  const int n   = blockIdx.x;
  const int hg  = l >> 5;
  const int lm  = l & 31;
  const int kq  = w * 1024;

  f32x16_t acc[2][2];
#pragma unroll
  for (int a = 0; a < 2; ++a)
#pragma unroll
    for (int c = 0; c < 2; ++c)
#pragma unroll
      for (int i = 0; i < 16; ++i) acc[a][c][i] = 0.0f;

  const char* vg  = (const char*)(vin + (size_t)n * D_DIM + kq) + hg * 32;
  const char* ua  = (const char*)(uf32 + (size_t)lm * D_DIM + kq) + hg * 32;
  const char* ubx = ua + (size_t)32 * D_DIM * 4;
  for (int s = 0; s < 64; ++s) {
    const float4 a0 = *(const float4*)(ua  + (size_t)s * 64);
    const float4 a1 = *(const float4*)(ua  + (size_t)s * 64 + 16);
    const float4 b0 = *(const float4*)(ubx + (size_t)s * 64);
    const float4 b1 = *(const float4*)(ubx + (size_t)s * 64 + 16);
    const float4 va = *(const float4*)(vg + s * 64);
    const float4 vb = *(const float4*)(vg + s * 64 + 16);
    Frag f0, f1, sa0, sa1;
    f0.u[0] = pk_bf16(a0.x, a0.y);  f0.u[1] = pk_bf16(a0.z, a0.w);
    f0.u[2] = pk_bf16(a1.x, a1.y);  f0.u[3] = pk_bf16(a1.z, a1.w);
    f1.u[0] = pk_bf16(b0.x, b0.y);  f1.u[1] = pk_bf16(b0.z, b0.w);
    f1.u[2] = pk_bf16(b1.x, b1.y);  f1.u[3] = pk_bf16(b1.z, b1.w);
    sa0.u[0] = pk_bf16(a0.x * va.x, a0.y * va.y);
    sa0.u[1] = pk_bf16(a0.z * va.z, a0.w * va.w);
    sa0.u[2] = pk_bf16(a1.x * vb.x, a1.y * vb.y);
    sa0.u[3] = pk_bf16(a1.z * vb.z, a1.w * vb.w);
    sa1.u[0] = pk_bf16(b0.x * va.x, b0.y * va.y);
    sa1.u[1] = pk_bf16(b0.z * va.z, b0.w * va.w);
    sa1.u[2] = pk_bf16(b1.x * vb.x, b1.y * vb.y);
    sa1.u[3] = pk_bf16(b1.z * vb.z, b1.w * vb.w);
    acc[0][0] = MFMA32B(sa0.b, f0.b, acc[0][0]);
    acc[0][1] = MFMA32B(sa0.b, f1.b, acc[0][1]);
    acc[1][0] = MFMA32B(sa1.b, f0.b, acc[1][0]);
    acc[1][1] = MFMA32B(sa1.b, f1.b, acc[1][1]);
  }

#pragma unroll
  for (int t = 0; t < 4; ++t) {
    __syncthreads();
    {
      const f32x16_t A = acc[t >> 1][t & 1];
      float* rp = &Red[w][l][0];
#pragma unroll
      for (int qq = 0; qq < 4; ++qq)
        *(float4*)(rp + qq * 4) =
            make_float4(A[qq * 4 + 0], A[qq * 4 + 1], A[qq * 4 + 2], A[qq * 4 + 3]);
    }
    __syncthreads();
    {
      const float4 r0 = *(const float4*)(&Red[0][l][w * 4]);
      const float4 r1 = *(const float4*)(&Red[1][l][w * 4]);
      const float4 r2 = *(const float4*)(&Red[2][l][w * 4]);
      const float4 r3 = *(const float4*)(&Red[3][l][w * 4]);
      const int tr = t >> 1, tc = t & 1;
      const int rbase = tr * 32 + w * 8 + ((l >> 5) << 2);
      const int col   = tc * 32 + (l & 31);
      float* op = out + (size_t)n * 4096 + (size_t)rbase * 64 + col;
      op[0]   = r0.x + r1.x + r2.x + r3.x;
      op[64]  = r0.y + r1.y + r2.y + r3.y;
      op[128] = r0.z + r1.z + r2.z + r3.z;
      op[192] = r0.w + r1.w + r2.w + r3.w;
    }
  }
}

extern "C" void kernel_launch(void* const* d_in, const int* in_sizes, int n_in,
                              void* d_out, int out_size, void* d_ws, size_t ws_size,
                              hipStream_t stream) {
  const float* v   = (const float*)d_in[0];
  const float* u   = (const float*)d_in[1];
  float*       out = (float*)d_out;
  if (ws_size >= ((size_t)4 << 20)) {
    _Float16* uh = (_Float16*)d_ws;
    _Float16* vh = (_Float16*)((char*)d_ws + VH_OFF);
    prep_kernel<<<dim3(640), dim3(256), 0, stream>>>(u, v, uh, vh);
    gram_kernel<<<dim3(N_DIM * 4), dim3(256), 0, stream>>>(vh, uh, out);
  } else {
    gram_fallback_kernel<<<dim3(N_DIM), dim3(256), 0, stream>>>(v, u, out);
  }
}

// Round 15
// 22.784 us; speedup vs baseline: 2.5116x; 2.5116x over previous
//
#include <hip/hip_runtime.h>
#include <stdint.h>

#define N_DIM 256
#define C_DIM 64
#define D_DIM 4096
#define NWAVE 16              // waves per block (K-split ways, in-block)
#define KWV   (D_DIM / NWAVE) // 256 k per wave
#define NSTEP (KWV / 16)      // 16 MFMA k-steps per wave
#define PDEP  4               // u prefetch pipeline depth

typedef __bf16    bf16x8_t __attribute__((ext_vector_type(8)));
typedef _Float16  f16x8_t  __attribute__((ext_vector_type(8)));
typedef float     f32x16_t __attribute__((ext_vector_type(16)));

union Frag {
  uint4     q;
  uint32_t  u[4];
  bf16x8_t  b;
};
union FragH {
  uint4     q;
  uint32_t  u[4];
  _Float16  h[8];
  f16x8_t   v;
};

__device__ __forceinline__ uint32_t pk_bf16(float lo, float hi) {
  uint32_t d;
  asm("v_cvt_pk_bf16_f32 %0, %1, %2" : "=v"(d) : "v"(lo), "v"(hi));
  return d;
}

__device__ __forceinline__ uint32_t pk_f16(float lo, float hi) {
  uint32_t d;
  asm("v_cvt_pkrtz_f16_f32 %0, %1, %2" : "=v"(d) : "v"(lo), "v"(hi));
  return d;
}

#define MFMA32H(a, b, c) __builtin_amdgcn_mfma_f32_32x32x16_f16(a, b, c, 0, 0, 0)
#define MFMA32B(a, b, c) __builtin_amdgcn_mfma_f32_32x32x16_bf16(a, b, c, 0, 0, 0)

// ---- prep: u f32 -> f16 subtile layout only (v handled in-kernel) ---------
// uh unit layout: [k8 = 0..511][row = 0..63][8 f16], 16 B per unit. (validated)
__global__ __launch_bounds__(512) void prep_kernel(const float* __restrict__ u,
                                                   _Float16* __restrict__ uh) {
  const int t   = blockIdx.x * 512 + threadIdx.x;   // 0..32767
  const int row = t >> 9;
  const int k8  = t & 511;
  const float4* p = (const float4*)(u + (size_t)row * D_DIM + (size_t)k8 * 8);
  const float4 a = p[0], b = p[1];
  FragH o;
  o.h[0] = (_Float16)a.x; o.h[1] = (_Float16)a.y;
  o.h[2] = (_Float16)a.z; o.h[3] = (_Float16)a.w;
  o.h[4] = (_Float16)b.x; o.h[5] = (_Float16)b.y;
  o.h[6] = (_Float16)b.z; o.h[7] = (_Float16)b.w;
  *(uint4*)(uh + (size_t)(k8 * C_DIM + row) * 8) = o.q;
}

// ---- gram: one 1024-thread block per n; 16-way K-split; symmetric 3-tile --
// R12-validated loop; v read directly as f32 (L1 broadcast) + in-reg convert.
__global__ __launch_bounds__(1024, 4)
void gram_kernel(const float* __restrict__ vin,
                 const _Float16* __restrict__ uh,
                 float* __restrict__ out)
{
  __shared__ float Red[NWAVE][C_DIM][17];   // 69.6 KB; odd stride -> 2/bank (free)

  const int tid = threadIdx.x;
  const int w   = tid >> 6;      // wave id = K-segment (0..15)
  const int l   = tid & 63;
  const int n   = blockIdx.x;
  const int hg  = l >> 5;
  const int lm  = l & 31;

  f32x16_t acc0, acc1, acc2;     // tiles (0,0), (1,0), (1,1); (0,1)=T(1,0)
#pragma unroll
  for (int i = 0; i < 16; ++i) { acc0[i] = 0.0f; acc1[i] = 0.0f; acc2[i] = 0.0f; }

  // v: direct f32 broadcast loads; wave slice = 1 KB f32, L1-resident lines
  const char* vg = (const char*)(vin + (size_t)n * D_DIM + w * KWV) + hg * 32;
  // u fragments: validated subtile addressing; k8 base = w*32 + hg
  const char* up = (const char*)uh + ((size_t)(w * 32 + hg)) * 1024 + (size_t)lm * 16;

  // PDEP-deep u pipeline (modular window; full unroll makes indices static)
  FragH pa[PDEP], pb[PDEP];
#pragma unroll
  for (int i = 0; i < PDEP; ++i) {
    pa[i].q = *(const uint4*)(up + i * 2048);
    pb[i].q = *(const uint4*)(up + i * 2048 + 512);
  }
  up += PDEP * 2048;

#pragma unroll
  for (int s = 0; s < NSTEP; ++s) {
    const int cur = s % PDEP;
    const float4 va = *(const float4*)(vg + s * 64);
    const float4 vb = *(const float4*)(vg + s * 64 + 16);
    FragH vv;
    vv.u[0] = pk_f16(va.x, va.y);
    vv.u[1] = pk_f16(va.z, va.w);
    vv.u[2] = pk_f16(vb.x, vb.y);
    vv.u[3] = pk_f16(vb.z, vb.w);
    FragH sa0, sa1;
    sa0.v = pa[cur].v * vv.v;     // v_pk_mul_f16
    sa1.v = pb[cur].v * vv.v;
    acc0 = MFMA32H(sa0.v, pa[cur].v, acc0);   // tile (0,0)
    acc1 = MFMA32H(sa1.v, pa[cur].v, acc1);   // tile (1,0)
    acc2 = MFMA32H(sa1.v, pb[cur].v, acc2);   // tile (1,1)
    if (s + PDEP < NSTEP) {       // guarded refill: no tail over-read
      pa[cur].q = *(const uint4*)(up);
      pb[cur].q = *(const uint4*)(up + 512);
      up += 2048;
    }
  }

  // ---- in-block K-reduction (16 partials) + direct out, 3 phases ----------
  // Producer (validated): acc tile (tr,tc) reg j of lane (hg,lm) ->
  //   row = tr*32 + 4*hg + (j&3) + 8*(j>>2), col = tc*32 + lm.
  // Reader (w,l) owns j = w; sums 16 waves. Phase 1 also stores the
  // transposed element into tile (0,1) (gram is symmetric).
  float* onb = out + (size_t)n * 4096;
#pragma unroll
  for (int p = 0; p < 3; ++p) {
    const int tr = (p >= 1) ? 1 : 0;
    const int tc = (p == 2) ? 1 : 0;
    __syncthreads();                 // Red free for reuse
    {
      const f32x16_t A = (p == 0) ? acc0 : (p == 1) ? acc1 : acc2;
      float* rp = &Red[w][l][0];
#pragma unroll
      for (int j = 0; j < 16; ++j)
        rp[j] = A[j];
    }
    __syncthreads();                 // all partials visible
    {
      float s = 0.0f;
#pragma unroll
      for (int ww = 0; ww < NWAVE; ++ww)
        s += Red[ww][l][w];
      const int row = tr * 32 + 4 * hg + (w & 3) + 8 * (w >> 2);
      const int col = tc * 32 + lm;
      onb[(size_t)row * 64 + col] = s;
      if (p == 1)                    // mirror into tile (0,1)
        onb[(size_t)col * 64 + row] = s;
    }
  }
}

// ---- fallback (tiny ws): R5/R6-validated single-kernel bf16 path ----------
__global__ __launch_bounds__(256)
void gram_fallback_kernel(const float* __restrict__ vin,
                          const float* __restrict__ uf32,
                          float* __restrict__ out)
{
  __shared__ float Red[4][C_DIM][20];

  const int tid = threadIdx.x;
  const int w   = tid >> 6;
  const int l   = tid & 63;
  const int n   = blockIdx.x;
  const int hg  = l >> 5;
  const int lm  = l & 31;
  const int kq  = w * 1024;

  f32x16_t acc[2][2];
#pragma unroll
  for (int a = 0; a < 2; ++a)
#pragma unroll
    for (int c = 0; c < 2; ++c)
#pragma unroll
      for (int i = 0; i < 16; ++i) acc[a][c][i] = 0.0f;

  const char* vg  = (const char*)(vin + (size_t)n * D_DIM + kq) + hg * 32;
  const char* ua  = (const char*)(uf32 + (size_t)lm * D_DIM + kq) + hg * 32;
  const char* ubx = ua + (size_t)32 * D_DIM * 4;
  for (int s = 0; s < 64; ++s) {
    const float4 a0 = *(const float4*)(ua  + (size_t)s * 64);
    const float4 a1 = *(const float4*)(ua  + (size_t)s * 64 + 16);
    const float4 b0 = *(const float4*)(ubx + (size_t)s * 64);
    const float4 b1 = *(const float4*)(ubx + (size_t)s * 64 + 16);
    const float4 va = *(const float4*)(vg + s * 64);
    const float4 vb = *(const float4*)(vg + s * 64 + 16);
    Frag f0, f1, sa0, sa1;
    f0.u[0] = pk_bf16(a0.x, a0.y);  f0.u[1] = pk_bf16(a0.z, a0.w);
    f0.u[2] = pk_bf16(a1.x, a1.y);  f0.u[3] = pk_bf16(a1.z, a1.w);
    f1.u[0] = pk_bf16(b0.x, b0.y);  f1.u[1] = pk_bf16(b0.z, b0.w);
    f1.u[2] = pk_bf16(b1.x, b1.y);  f1.u[3] = pk_bf16(b1.z, b1.w);
    sa0.u[0] = pk_bf16(a0.x * va.x, a0.y * va.y);
    sa0.u[1] = pk_bf16(a0.z * va.z, a0.w * va.w);
    sa0.u[2] = pk_bf16(a1.x * vb.x, a1.y * vb.y);
    sa0.u[3] = pk_bf16(a1.z * vb.z, a1.w * vb.w);
    sa1.u[0] = pk_bf16(b0.x * va.x, b0.y * va.y);
    sa1.u[1] = pk_bf16(b0.z * va.z, b0.w * va.w);
    sa1.u[2] = pk_bf16(b1.x * vb.x, b1.y * vb.y);
    sa1.u[3] = pk_bf16(b1.z * vb.z, b1.w * vb.w);
    acc[0][0] = MFMA32B(sa0.b, f0.b, acc[0][0]);
    acc[0][1] = MFMA32B(sa0.b, f1.b, acc[0][1]);
    acc[1][0] = MFMA32B(sa1.b, f0.b, acc[1][0]);
    acc[1][1] = MFMA32B(sa1.b, f1.b, acc[1][1]);
  }

#pragma unroll
  for (int t = 0; t < 4; ++t) {
    __syncthreads();
    {
      const f32x16_t A = acc[t >> 1][t & 1];
      float* rp = &Red[w][l][0];
#pragma unroll
      for (int qq = 0; qq < 4; ++qq)
        *(float4*)(rp + qq * 4) =
            make_float4(A[qq * 4 + 0], A[qq * 4 + 1], A[qq * 4 + 2], A[qq * 4 + 3]);
    }
    __syncthreads();
    {
      const float4 r0 = *(const float4*)(&Red[0][l][w * 4]);
      const float4 r1 = *(const float4*)(&Red[1][l][w * 4]);
      const float4 r2 = *(const float4*)(&Red[2][l][w * 4]);
      const float4 r3 = *(const float4*)(&Red[3][l][w * 4]);
      const int tr = t >> 1, tc = t & 1;
      const int rbase = tr * 32 + w * 8 + ((l >> 5) << 2);
      const int col   = tc * 32 + (l & 31);
      float* op = out + (size_t)n * 4096 + (size_t)rbase * 64 + col;
      op[0]   = r0.x + r1.x + r2.x + r3.x;
      op[64]  = r0.y + r1.y + r2.y + r3.y;
      op[128] = r0.z + r1.z + r2.z + r3.z;
      op[192] = r0.w + r1.w + r2.w + r3.w;
    }
  }
}

extern "C" void kernel_launch(void* const* d_in, const int* in_sizes, int n_in,
                              void* d_out, int out_size, void* d_ws, size_t ws_size,
                              hipStream_t stream) {
  const float* v   = (const float*)d_in[0];
  const float* u   = (const float*)d_in[1];
  float*       out = (float*)d_out;
  if (ws_size >= ((size_t)1 << 20)) {   // 512 KB f16 u (no over-read: guarded)
    _Float16* uh = (_Float16*)d_ws;
    prep_kernel<<<dim3(64), dim3(512), 0, stream>>>(u, uh);
    gram_kernel<<<dim3(N_DIM), dim3(1024), 0, stream>>>(v, uh, out);
  } else {
    gram_fallback_kernel<<<dim3(N_DIM), dim3(256), 0, stream>>>(v, u, out);
  }
}